// Round 1
// 818.826 us; speedup vs baseline: 1.1704x; 1.1704x over previous
//
#include <hip/hip_runtime.h>
#include <math.h>

// NonlinearFilter — Round 3: transposed-output MFMA restructure.
// 4 waves (256 thr), one workgroup per batch element.
// Key idea: compute GEMMs as mfma(W^T_frag, x_frag) so the OUTPUT tile is
// transposed: lane owns s = lane&15 and 4 consecutive output columns.
//  - GEMM1 epilogue: packed bf16x4 ds_write_b64, conflict-free (vs scalar b16
//    writes that caused 2.65e7 bank-conflict cycles).
//  - GEMM2 epilogue: each wave owns 16 l-columns for BOTH s-halves -> moments
//    reduce via 16-lane shfl_xor butterfly, Kalman redundant-per-lane in regs,
//    and the SAME thread that samples z keeps it in registers as next step's
//    fp32 residual (sZf buffer + 2 of 4 barriers eliminated).
//  - libm tanhf -> exp2-based fast tanh (saturates correctly at +-inf).
//  - lo*lo split-bf16 cross term dropped (~2^-18 rel, noise vs 0.0625 absmax).

namespace {
constexpr int B = 128;
constexpr int T = 256;
constexpr int L = 64;
constexpr int S = 25;
constexpr int H = 128;
constexpr int NT = 256;          // 4 waves
constexpr int LP = 72;           // bf16 row stride, 64-wide tiles (z, W1^T) -> 36 dw: conflict-free b128 frag reads
constexpr int HP = 136;          // bf16 row stride, 128-wide tiles (th, W2^T) -> 68 dw: conflict-free

typedef __bf16 bf16x8 __attribute__((ext_vector_type(8)));
typedef __bf16 bf16x4 __attribute__((ext_vector_type(4)));
typedef float floatx4 __attribute__((ext_vector_type(4)));

__device__ __forceinline__ float softplus_f(float x) {
    return fmaxf(x, 0.0f) + log1pf(expf(-fabsf(x)));
}

// tanh(x) = 1 - 2/(e^{2x}+1). v_exp_f32 + v_rcp_f32; x->+inf: e=inf -> rcp=0 -> 1;
// x->-inf: e=0 -> 1-2 = -1. ~1e-7 abs error, far below the split-bf16 budget.
__device__ __forceinline__ float tanh_fast(float x) {
    const float e = __builtin_amdgcn_exp2f(x * 2.885390081777927f); // 2*log2(e)
    return 1.0f - 2.0f * __builtin_amdgcn_rcpf(e + 1.0f);
}

__device__ __forceinline__ void split4(const float v[4], bf16x4* h, bf16x4* l) {
    #pragma unroll
    for (int r = 0; r < 4; ++r) {
        const __bf16 hi = (__bf16)v[r];
        (*h)[r] = hi;
        (*l)[r] = (__bf16)(v[r] - (float)hi);
    }
}
} // namespace

__global__ __launch_bounds__(NT, 1)
void nlf_kernel(const float* __restrict__ kk,
                const float* __restrict__ KK,
                const float* __restrict__ noise,
                const float* __restrict__ log_Q,
                const float* __restrict__ m_0,
                const float* __restrict__ log_Q_0,
                const float* __restrict__ W1,
                const float* __restrict__ b1,
                const float* __restrict__ W2,
                const float* __restrict__ b2,
                float* __restrict__ out)
{
    const int b    = blockIdx.x;
    const int tid  = threadIdx.x;
    const int w    = tid >> 6;        // wave 0..3: owns l-columns [w*16, w*16+16)
    const int lane = tid & 63;
    const int r16  = lane & 15;       // = sample index s (and s+16) in epilogues
    const int q    = lane >> 4;
    const int lc   = w * 16 + q * 4;  // this thread's 4 output l-columns

    // weights, transposed, split hi/lo
    __shared__ __align__(16) __bf16 sW1h[H][LP];   // W1^T: [j][k]
    __shared__ __align__(16) __bf16 sW1l[H][LP];
    __shared__ __align__(16) __bf16 sW2h[L][HP];   // W2^T: [l][j]
    __shared__ __align__(16) __bf16 sW2l[L][HP];
    // state
    __shared__ __align__(16) __bf16 sThh[32][HP];  // th: [s][j], rows 25..31 = tanh(b1) pad
    __shared__ __align__(16) __bf16 sThl[32][HP];
    __shared__ __align__(16) __bf16 sZh[32][LP];   // z: [s][k], rows 25..31 zero
    __shared__ __align__(16) __bf16 sZl[32][LP];

    // ---- stage weights (once) ----
    for (int i = tid; i < L * H; i += NT) {      // W1 (L rows, H cols)
        const int l = i >> 7, j = i & 127;
        const float v = W1[i];
        const __bf16 hi = (__bf16)v;
        sW1h[j][l] = hi;
        sW1l[j][l] = (__bf16)(v - (float)hi);
    }
    for (int i = tid; i < H * L; i += NT) {      // W2 (H rows, L cols)
        const int j = i >> 6, l2 = i & 63;
        const float v = W2[i];
        const __bf16 hi = (__bf16)v;
        sW2h[l2][j] = hi;
        sW2l[l2][j] = (__bf16)(v - (float)hi);
    }
    for (int i = tid; i < 7 * LP; i += NT) {     // zero z pad rows 25..31 (never rewritten)
        sZh[25 + i / LP][i % LP] = (__bf16)0.0f;
        sZl[25 + i / LP][i % LP] = (__bf16)0.0f;
    }

    // ---- per-thread constants in registers ----
    const float4 b2v = *(const float4*)&b2[lc];
    float4 b1v[2];
    b1v[0] = *(const float4*)&b1[(2 * w    ) * 16 + q * 4];
    b1v[1] = *(const float4*)&b1[(2 * w + 1) * 16 + q * 4];
    float qd4[4];
    #pragma unroll
    for (int r = 0; r < 4; ++r) qd4[r] = softplus_f(log_Q[lc + r]);

    float* out_zf = out;                                  // (S,B,T,L)
    float* out_mf = out + (size_t)S * B * T * L;          // (B,T,L)
    float* out_mp = out_mf + (size_t)B * T * L;
    float* out_Pf = out_mp + (size_t)B * T * L;
    float* out_Pp = out_Pf + (size_t)B * T * L;

    const bool m1ok = (r16 < S - 16);  // second s-half valid: s = 16+r16 <= 24

    float zreg0[4];                    // fp32 z at (s=r16,   lc..lc+3) — exact residual
    float zreg1[4] = {0.f, 0.f, 0.f, 0.f};  // at (s=16+r16, ...) if m1ok

    // ---- t = 0 ----
    {
        const float4 lq0 = *(const float4*)&log_Q_0[lc];
        const float4 m0v = *(const float4*)&m_0[lc];
        const float4 K0  = *(const float4*)&KK[((size_t)b * T + 0) * L + lc];
        const float4 k0  = *(const float4*)&kk[((size_t)b * T + 0) * L + lc];
        float mfv[4], spv[4];
        float4 mf4, pf4, pp4;
        #pragma unroll
        for (int r = 0; r < 4; ++r) {
            const float P0 = softplus_f((&lq0.x)[r]);
            const float J0 = 1.0f / P0;
            const float Jf = J0 + (&K0.x)[r];
            const float Pf = 1.0f / Jf;
            const float mf = Pf * (J0 * (&m0v.x)[r] + (&k0.x)[r]);
            mfv[r] = mf;
            spv[r] = sqrtf(Pf);
            (&mf4.x)[r] = mf; (&pf4.x)[r] = Pf; (&pp4.x)[r] = P0;
        }
        if (r16 == 0) {
            const size_t o = ((size_t)b * T + 0) * L + lc;
            *(float4*)&out_mf[o] = mf4;
            *(float4*)&out_mp[o] = m0v;
            *(float4*)&out_Pf[o] = pf4;
            *(float4*)&out_Pp[o] = pp4;
        }
        {   // sample s = r16
            const float4 nv = *(const float4*)&noise[(((size_t)0 * S + r16) * B + b) * L + lc];
            float zv[4];
            #pragma unroll
            for (int r = 0; r < 4; ++r) { zv[r] = fmaf(spv[r], (&nv.x)[r], mfv[r]); zreg0[r] = zv[r]; }
            bf16x4 h, l; split4(zv, &h, &l);
            *(bf16x4*)&sZh[r16][lc] = h;
            *(bf16x4*)&sZl[r16][lc] = l;
            *(float4*)&out_zf[(((size_t)r16 * B + b) * T + 0) * L + lc] = make_float4(zv[0], zv[1], zv[2], zv[3]);
        }
        if (m1ok) {  // sample s = 16 + r16
            const int s = 16 + r16;
            const float4 nv = *(const float4*)&noise[(((size_t)0 * S + s) * B + b) * L + lc];
            float zv[4];
            #pragma unroll
            for (int r = 0; r < 4; ++r) { zv[r] = fmaf(spv[r], (&nv.x)[r], mfv[r]); zreg1[r] = zv[r]; }
            bf16x4 h, l; split4(zv, &h, &l);
            *(bf16x4*)&sZh[s][lc] = h;
            *(bf16x4*)&sZl[s][lc] = l;
            *(float4*)&out_zf[(((size_t)s * B + b) * T + 0) * L + lc] = make_float4(zv[0], zv[1], zv[2], zv[3]);
        }
    }

    // ---- main scan: 2 barriers per step ----
    for (int t = 1; t < T; ++t) {
        const size_t bt = (size_t)b * T + t;
        // prefetch per-step inputs (consumed at end of step — latency hidden)
        const float4 kv = *(const float4*)&kk[bt * L + lc];
        const float4 Kv = *(const float4*)&KK[bt * L + lc];
        const float4 nv0 = *(const float4*)&noise[(((size_t)t * S + r16) * B + b) * L + lc];
        float4 nv1 = make_float4(0.f, 0.f, 0.f, 0.f);
        if (m1ok) nv1 = *(const float4*)&noise[(((size_t)t * S + 16 + r16) * B + b) * L + lc];

        __syncthreads();   // prev sample's sZ writes -> GEMM1 reads

        // ===== GEMM1 (transposed): D[j][s] = mfma(W1T_frag, z_frag)
        // wave w covers j-tiles {2w, 2w+1} x both s-halves; 6 MFMA per tile.
        bf16x8 z0h[2], z0l[2], z1h[2], z1l[2];
        #pragma unroll
        for (int kb = 0; kb < 2; ++kb) {
            z0h[kb] = *(const bf16x8*)&sZh[r16][kb * 32 + q * 8];
            z0l[kb] = *(const bf16x8*)&sZl[r16][kb * 32 + q * 8];
            z1h[kb] = *(const bf16x8*)&sZh[16 + r16][kb * 32 + q * 8];
            z1l[kb] = *(const bf16x8*)&sZl[16 + r16][kb * 32 + q * 8];
        }
        #pragma unroll
        for (int tt = 0; tt < 2; ++tt) {
            const int jt = 2 * w + tt;
            floatx4 c0 = {0.f, 0.f, 0.f, 0.f};
            floatx4 c1 = {0.f, 0.f, 0.f, 0.f};
            #pragma unroll
            for (int kb = 0; kb < 2; ++kb) {
                const bf16x8 wh = *(const bf16x8*)&sW1h[jt * 16 + r16][kb * 32 + q * 8];
                const bf16x8 wl = *(const bf16x8*)&sW1l[jt * 16 + r16][kb * 32 + q * 8];
                c0 = __builtin_amdgcn_mfma_f32_16x16x32_bf16(wh, z0h[kb], c0, 0, 0, 0);
                c0 = __builtin_amdgcn_mfma_f32_16x16x32_bf16(wl, z0h[kb], c0, 0, 0, 0);
                c0 = __builtin_amdgcn_mfma_f32_16x16x32_bf16(wh, z0l[kb], c0, 0, 0, 0);
                c1 = __builtin_amdgcn_mfma_f32_16x16x32_bf16(wh, z1h[kb], c1, 0, 0, 0);
                c1 = __builtin_amdgcn_mfma_f32_16x16x32_bf16(wl, z1h[kb], c1, 0, 0, 0);
                c1 = __builtin_amdgcn_mfma_f32_16x16x32_bf16(wh, z1l[kb], c1, 0, 0, 0);
            }
            // epilogue: tanh + split, packed b64 writes (conflict-free)
            float tv[4];
            bf16x4 h, l;
            #pragma unroll
            for (int r = 0; r < 4; ++r) tv[r] = tanh_fast(c0[r] + (&b1v[tt].x)[r]);
            split4(tv, &h, &l);
            *(bf16x4*)&sThh[r16][jt * 16 + q * 4] = h;
            *(bf16x4*)&sThl[r16][jt * 16 + q * 4] = l;
            #pragma unroll
            for (int r = 0; r < 4; ++r) tv[r] = tanh_fast(c1[r] + (&b1v[tt].x)[r]);
            split4(tv, &h, &l);
            *(bf16x4*)&sThh[16 + r16][jt * 16 + q * 4] = h;
            *(bf16x4*)&sThl[16 + r16][jt * 16 + q * 4] = l;
        }
        __syncthreads();   // sTh writes -> GEMM2 reads

        // ===== GEMM2 (transposed): D[l][s] = mfma(W2T_frag, th_frag), K=128
        floatx4 d0 = {0.f, 0.f, 0.f, 0.f};
        floatx4 d1 = {0.f, 0.f, 0.f, 0.f};
        #pragma unroll
        for (int kb = 0; kb < 4; ++kb) {
            const bf16x8 ah  = *(const bf16x8*)&sW2h[w * 16 + r16][kb * 32 + q * 8];
            const bf16x8 al  = *(const bf16x8*)&sW2l[w * 16 + r16][kb * 32 + q * 8];
            const bf16x8 t0h = *(const bf16x8*)&sThh[r16][kb * 32 + q * 8];
            const bf16x8 t0l = *(const bf16x8*)&sThl[r16][kb * 32 + q * 8];
            const bf16x8 t1h = *(const bf16x8*)&sThh[16 + r16][kb * 32 + q * 8];
            const bf16x8 t1l = *(const bf16x8*)&sThl[16 + r16][kb * 32 + q * 8];
            d0 = __builtin_amdgcn_mfma_f32_16x16x32_bf16(ah, t0h, d0, 0, 0, 0);
            d0 = __builtin_amdgcn_mfma_f32_16x16x32_bf16(al, t0h, d0, 0, 0, 0);
            d0 = __builtin_amdgcn_mfma_f32_16x16x32_bf16(ah, t0l, d0, 0, 0, 0);
            d1 = __builtin_amdgcn_mfma_f32_16x16x32_bf16(ah, t1h, d1, 0, 0, 0);
            d1 = __builtin_amdgcn_mfma_f32_16x16x32_bf16(al, t1h, d1, 0, 0, 0);
            d1 = __builtin_amdgcn_mfma_f32_16x16x32_bf16(ah, t1l, d1, 0, 0, 0);
        }

        // ===== moments: residual from registers, butterfly reduce over s
        float sm[4], sq[4];
        #pragma unroll
        for (int r = 0; r < 4; ++r) {
            const float v0  = d0[r] + (&b2v.x)[r] + zreg0[r];
            const float v1  = d1[r] + (&b2v.x)[r] + zreg1[r];
            const float v1m = m1ok ? v1 : 0.0f;
            sm[r] = v0 + v1m;
            sq[r] = fmaf(v0, v0, v1m * v1m);
        }
        #pragma unroll
        for (int d = 1; d < 16; d <<= 1) {
            #pragma unroll
            for (int r = 0; r < 4; ++r) {
                sm[r] += __shfl_xor(sm[r], d);
                sq[r] += __shfl_xor(sq[r], d);
            }
        }

        // ===== Kalman (redundant per lane, all in registers)
        float mfv[4], spv[4];
        float4 mf4, mp4, pf4, pp4;
        #pragma unroll
        for (int r = 0; r < 4; ++r) {
            const float mp  = sm[r] * (1.0f / S);
            const float msq = sq[r] * (1.0f / S);
            const float Pp  = qd4[r] + msq - mp * mp;
            const float Jp  = __builtin_amdgcn_rcpf(Pp);
            const float Jf  = Jp + (&Kv.x)[r];
            const float Pf  = __builtin_amdgcn_rcpf(Jf);
            const float mf  = Pf * fmaf(Jp, mp, (&kv.x)[r]);
            mfv[r] = mf;
            spv[r] = __builtin_amdgcn_sqrtf(Pf);
            (&mf4.x)[r] = mf; (&mp4.x)[r] = mp; (&pf4.x)[r] = Pf; (&pp4.x)[r] = Pp;
        }
        if (r16 == 0) {
            const size_t o = bt * L + lc;
            *(float4*)&out_mf[o] = mf4;
            *(float4*)&out_mp[o] = mp4;
            *(float4*)&out_Pf[o] = pf4;
            *(float4*)&out_Pp[o] = pp4;
        }

        // ===== sample z_t (same thread keeps fp32 z for next step's residual)
        {
            float zv[4];
            #pragma unroll
            for (int r = 0; r < 4; ++r) { zv[r] = fmaf(spv[r], (&nv0.x)[r], mfv[r]); zreg0[r] = zv[r]; }
            bf16x4 h, l; split4(zv, &h, &l);
            *(bf16x4*)&sZh[r16][lc] = h;
            *(bf16x4*)&sZl[r16][lc] = l;
            *(float4*)&out_zf[(((size_t)r16 * B + b) * T + t) * L + lc] = make_float4(zv[0], zv[1], zv[2], zv[3]);
        }
        if (m1ok) {
            const int s = 16 + r16;
            float zv[4];
            #pragma unroll
            for (int r = 0; r < 4; ++r) { zv[r] = fmaf(spv[r], (&nv1.x)[r], mfv[r]); zreg1[r] = zv[r]; }
            bf16x4 h, l; split4(zv, &h, &l);
            *(bf16x4*)&sZh[s][lc] = h;
            *(bf16x4*)&sZl[s][lc] = l;
            *(float4*)&out_zf[(((size_t)s * B + b) * T + t) * L + lc] = make_float4(zv[0], zv[1], zv[2], zv[3]);
        }
    }
}

extern "C" void kernel_launch(void* const* d_in, const int* in_sizes, int n_in,
                              void* d_out, int out_size, void* d_ws, size_t ws_size,
                              hipStream_t stream) {
    const float* kk      = (const float*)d_in[0];
    const float* KK      = (const float*)d_in[1];
    const float* noise   = (const float*)d_in[2];
    const float* log_Q   = (const float*)d_in[3];
    const float* m_0     = (const float*)d_in[4];
    const float* log_Q_0 = (const float*)d_in[5];
    const float* W1      = (const float*)d_in[6];
    const float* b1      = (const float*)d_in[7];
    const float* W2      = (const float*)d_in[8];
    const float* b2      = (const float*)d_in[9];
    float* outp          = (float*)d_out;

    nlf_kernel<<<dim3(B), dim3(NT), 0, stream>>>(
        kk, KK, noise, log_Q, m_0, log_Q_0, W1, b1, W2, b2, outp);
}

// Round 2
// 717.425 us; speedup vs baseline: 1.3358x; 1.1413x over previous
//
#include <hip/hip_runtime.h>
#include <math.h>

// NonlinearFilter — Round 4: latency-exposure attack (1 wave/SIMD regime).
//  - Raw lgkmcnt-only barriers (HK pattern): __syncthreads() drains vmcnt(0),
//    exposing prefetch-load + store-ack latency twice per step. Barriers here
//    only order LDS (sZ -> GEMM1, sTh -> GEMM2), so lgkmcnt(0)+s_barrier is
//    sufficient; global loads/stores stay in flight across steps.
//  - Weight fragments (W1^T, W2^T hi/lo) hoisted to registers ONCE: they are
//    t-invariant. Removes 16 of 40 LDS b128 reads per step (+their conflicts).
//    +64 VGPR is free: 132->~200, still 1 wave/SIMD.
//  - 16-lane moment reduction via DPP v_add_f32 (row_ror:8/4 + quad_perm
//    xor2/xor1) instead of 32 ds-shuffle ops: pure VALU, no DS latency chain.
//  - All per-step global addresses as hoisted strided pointers.

namespace {
constexpr int B = 128;
constexpr int T = 256;
constexpr int L = 64;
constexpr int S = 25;
constexpr int H = 128;
constexpr int NT = 256;          // 4 waves
constexpr int LP = 72;           // bf16 row stride for 64-wide tiles (z, W1^T)
constexpr int HP = 136;          // bf16 row stride for 128-wide tiles (th, W2^T)

typedef __bf16 bf16x8 __attribute__((ext_vector_type(8)));
typedef __bf16 bf16x4 __attribute__((ext_vector_type(4)));
typedef float floatx4 __attribute__((ext_vector_type(4)));

__device__ __forceinline__ float softplus_f(float x) {
    return fmaxf(x, 0.0f) + log1pf(expf(-fabsf(x)));
}

// tanh(x) = 1 - 2/(e^{2x}+1); saturates correctly at +-inf. ~1e-7 abs err.
__device__ __forceinline__ float tanh_fast(float x) {
    const float e = __builtin_amdgcn_exp2f(x * 2.885390081777927f); // 2*log2(e)
    return 1.0f - 2.0f * __builtin_amdgcn_rcpf(e + 1.0f);
}

__device__ __forceinline__ void split4(const float v[4], bf16x4* h, bf16x4* l) {
    #pragma unroll
    for (int r = 0; r < 4; ++r) {
        const __bf16 hi = (__bf16)v[r];
        (*h)[r] = hi;
        (*l)[r] = (__bf16)(v[r] - (float)hi);
    }
}

// x += shuffled(x) via DPP — single v_add_f32_dpp after folding.
template<int CTRL>
__device__ __forceinline__ float dpp_radd(float x) {
    const int yi = __builtin_amdgcn_update_dpp(
        0, __builtin_bit_cast(int, x), CTRL, 0xf, 0xf, false);
    return x + __builtin_bit_cast(float, yi);
}
// Full sum over each row of 16 lanes (all 16 lanes get the result).
__device__ __forceinline__ float reduce16(float x) {
    x = dpp_radd<0x128>(x);  // row_ror:8  -> pairs (i, i+8)
    x = dpp_radd<0x124>(x);  // row_ror:4  -> quads
    x = dpp_radd<0x4E>(x);   // quad_perm [2,3,0,1] -> xor2
    x = dpp_radd<0xB1>(x);   // quad_perm [1,0,3,2] -> xor1
    return x;
}

// LDS-only barrier: order ds_writes -> barrier -> ds_reads without draining
// vmcnt (global loads/stores stay in flight). Memory-clobber asm fences stop
// the compiler from moving LDS ops across it (guide §5 template / m201).
__device__ __forceinline__ void lds_barrier() {
    asm volatile("s_waitcnt lgkmcnt(0)" ::: "memory");
    __builtin_amdgcn_s_barrier();
    asm volatile("" ::: "memory");
}
} // namespace

__global__ __launch_bounds__(NT, 1)
void nlf_kernel(const float* __restrict__ kk,
                const float* __restrict__ KK,
                const float* __restrict__ noise,
                const float* __restrict__ log_Q,
                const float* __restrict__ m_0,
                const float* __restrict__ log_Q_0,
                const float* __restrict__ W1,
                const float* __restrict__ b1,
                const float* __restrict__ W2,
                const float* __restrict__ b2,
                float* __restrict__ out)
{
    const int b    = blockIdx.x;
    const int tid  = threadIdx.x;
    const int w    = tid >> 6;        // wave 0..3: owns l-columns [w*16, w*16+16)
    const int lane = tid & 63;
    const int r16  = lane & 15;       // sample index s (and s+16) in epilogues
    const int q    = lane >> 4;
    const int lc   = w * 16 + q * 4;  // this thread's 4 output l-columns

    // weights staged once (transposed, split hi/lo), then hoisted to VGPRs
    __shared__ __align__(16) __bf16 sW1h[H][LP];   // W1^T: [j][k]
    __shared__ __align__(16) __bf16 sW1l[H][LP];
    __shared__ __align__(16) __bf16 sW2h[L][HP];   // W2^T: [l][j]
    __shared__ __align__(16) __bf16 sW2l[L][HP];
    // state
    __shared__ __align__(16) __bf16 sThh[32][HP];  // th: [s][j]
    __shared__ __align__(16) __bf16 sThl[32][HP];
    __shared__ __align__(16) __bf16 sZh[32][LP];   // z: [s][k], rows 25..31 zero
    __shared__ __align__(16) __bf16 sZl[32][LP];

    // ---- stage weights (once) ----
    for (int i = tid; i < L * H; i += NT) {      // W1 (L rows, H cols)
        const int l = i >> 7, j = i & 127;
        const float v = W1[i];
        const __bf16 hi = (__bf16)v;
        sW1h[j][l] = hi;
        sW1l[j][l] = (__bf16)(v - (float)hi);
    }
    for (int i = tid; i < H * L; i += NT) {      // W2 (H rows, L cols)
        const int j = i >> 6, l2 = i & 63;
        const float v = W2[i];
        const __bf16 hi = (__bf16)v;
        sW2h[l2][j] = hi;
        sW2l[l2][j] = (__bf16)(v - (float)hi);
    }
    for (int i = tid; i < 7 * LP; i += NT) {     // zero z pad rows 25..31
        sZh[25 + i / LP][i % LP] = (__bf16)0.0f;
        sZl[25 + i / LP][i % LP] = (__bf16)0.0f;
    }
    __syncthreads();

    // ---- hoist weight fragments into registers (t-invariant) ----
    bf16x8 w1h[2][2], w1l[2][2];     // [tt][kb] for j-tile 2w+tt, k-block kb
    #pragma unroll
    for (int tt = 0; tt < 2; ++tt)
        #pragma unroll
        for (int kb = 0; kb < 2; ++kb) {
            w1h[tt][kb] = *(const bf16x8*)&sW1h[(2 * w + tt) * 16 + r16][kb * 32 + q * 8];
            w1l[tt][kb] = *(const bf16x8*)&sW1l[(2 * w + tt) * 16 + r16][kb * 32 + q * 8];
        }
    bf16x8 w2h[4], w2l[4];           // [kb] for l-tile w
    #pragma unroll
    for (int kb = 0; kb < 4; ++kb) {
        w2h[kb] = *(const bf16x8*)&sW2h[w * 16 + r16][kb * 32 + q * 8];
        w2l[kb] = *(const bf16x8*)&sW2l[w * 16 + r16][kb * 32 + q * 8];
    }

    // ---- per-thread constants ----
    const float4 b2v = *(const float4*)&b2[lc];
    float4 b1v[2];
    b1v[0] = *(const float4*)&b1[(2 * w    ) * 16 + q * 4];
    b1v[1] = *(const float4*)&b1[(2 * w + 1) * 16 + q * 4];
    float qd4[4];
    #pragma unroll
    for (int r = 0; r < 4; ++r) qd4[r] = softplus_f(log_Q[lc + r]);

    float* out_zf = out;                                  // (S,B,T,L)
    float* out_mf = out + (size_t)S * B * T * L;          // (B,T,L)
    float* out_mp = out_mf + (size_t)B * T * L;
    float* out_Pf = out_mp + (size_t)B * T * L;
    float* out_Pp = out_Pf + (size_t)B * T * L;

    const bool m1ok = (r16 < S - 16);  // second s-half valid: s = 16+r16 <= 24

    float zreg0[4];                         // fp32 z at (s=r16, lc..lc+3)
    float zreg1[4] = {0.f, 0.f, 0.f, 0.f};  // at (s=16+r16) if m1ok

    // ---- t = 0 ----
    {
        const float4 lq0 = *(const float4*)&log_Q_0[lc];
        const float4 m0v = *(const float4*)&m_0[lc];
        const float4 K0  = *(const float4*)&KK[((size_t)b * T + 0) * L + lc];
        const float4 k0  = *(const float4*)&kk[((size_t)b * T + 0) * L + lc];
        float mfv[4], spv[4];
        float4 mf4, pf4, pp4;
        #pragma unroll
        for (int r = 0; r < 4; ++r) {
            const float P0 = softplus_f((&lq0.x)[r]);
            const float J0 = 1.0f / P0;
            const float Jf = J0 + (&K0.x)[r];
            const float Pf = 1.0f / Jf;
            const float mf = Pf * (J0 * (&m0v.x)[r] + (&k0.x)[r]);
            mfv[r] = mf;
            spv[r] = sqrtf(Pf);
            (&mf4.x)[r] = mf; (&pf4.x)[r] = Pf; (&pp4.x)[r] = P0;
        }
        if (r16 == 0) {
            const size_t o = ((size_t)b * T + 0) * L + lc;
            *(float4*)&out_mf[o] = mf4;
            *(float4*)&out_mp[o] = m0v;
            *(float4*)&out_Pf[o] = pf4;
            *(float4*)&out_Pp[o] = pp4;
        }
        {   // sample s = r16
            const float4 nv = *(const float4*)&noise[(((size_t)0 * S + r16) * B + b) * L + lc];
            float zv[4];
            #pragma unroll
            for (int r = 0; r < 4; ++r) { zv[r] = fmaf(spv[r], (&nv.x)[r], mfv[r]); zreg0[r] = zv[r]; }
            bf16x4 h, l; split4(zv, &h, &l);
            *(bf16x4*)&sZh[r16][lc] = h;
            *(bf16x4*)&sZl[r16][lc] = l;
            *(float4*)&out_zf[(((size_t)r16 * B + b) * T + 0) * L + lc] = make_float4(zv[0], zv[1], zv[2], zv[3]);
        }
        if (m1ok) {  // sample s = 16 + r16
            const int s = 16 + r16;
            const float4 nv = *(const float4*)&noise[(((size_t)0 * S + s) * B + b) * L + lc];
            float zv[4];
            #pragma unroll
            for (int r = 0; r < 4; ++r) { zv[r] = fmaf(spv[r], (&nv.x)[r], mfv[r]); zreg1[r] = zv[r]; }
            bf16x4 h, l; split4(zv, &h, &l);
            *(bf16x4*)&sZh[s][lc] = h;
            *(bf16x4*)&sZl[s][lc] = l;
            *(float4*)&out_zf[(((size_t)s * B + b) * T + 0) * L + lc] = make_float4(zv[0], zv[1], zv[2], zv[3]);
        }
    }

    // ---- hoisted strided pointers (start at t=1) ----
    constexpr size_t DSEC  = (size_t)B * T * L;   // out section stride
    constexpr size_t NSTEP = (size_t)S * B * L;   // noise t-stride
    const float* pk  = kk    + ((size_t)b * T + 1) * L + lc;
    const float* pK  = KK    + ((size_t)b * T + 1) * L + lc;
    const float* pn0 = noise + (((size_t)1 * S + r16) * B + b) * L + lc;
    const float* pn1 = noise + (((size_t)1 * S + 16 + r16) * B + b) * L + lc;
    float* pz0 = out_zf + (((size_t)r16 * B + b) * T + 1) * L + lc;
    float* pz1 = out_zf + (((size_t)(16 + r16) * B + b) * T + 1) * L + lc;
    float* pmf = out_mf + ((size_t)b * T + 1) * L + lc;

    // ---- main scan: 2 LDS-only barriers per step ----
    for (int t = 1; t < T; ++t) {
        // prefetch per-step inputs; with lgkm-only barriers these stay in
        // flight until their true use (Kalman / sampling) at step end.
        const float4 kv  = *(const float4*)pk;
        const float4 Kv  = *(const float4*)pK;
        const float4 nv0 = *(const float4*)pn0;
        float4 nv1 = make_float4(0.f, 0.f, 0.f, 0.f);
        if (m1ok) nv1 = *(const float4*)pn1;
        pk += L; pK += L; pn0 += NSTEP; pn1 += NSTEP;

        lds_barrier();   // B1: prev sample's sZ writes -> GEMM1 reads

        // ===== GEMM1 (transposed): D[j][s] = mfma(W1T_frag, z_frag)
        bf16x8 z0h[2], z0l[2], z1h[2], z1l[2];
        #pragma unroll
        for (int kb = 0; kb < 2; ++kb) {
            z0h[kb] = *(const bf16x8*)&sZh[r16][kb * 32 + q * 8];
            z0l[kb] = *(const bf16x8*)&sZl[r16][kb * 32 + q * 8];
            z1h[kb] = *(const bf16x8*)&sZh[16 + r16][kb * 32 + q * 8];
            z1l[kb] = *(const bf16x8*)&sZl[16 + r16][kb * 32 + q * 8];
        }
        #pragma unroll
        for (int tt = 0; tt < 2; ++tt) {
            floatx4 c0 = {0.f, 0.f, 0.f, 0.f};
            floatx4 c1 = {0.f, 0.f, 0.f, 0.f};
            #pragma unroll
            for (int kb = 0; kb < 2; ++kb) {
                c0 = __builtin_amdgcn_mfma_f32_16x16x32_bf16(w1h[tt][kb], z0h[kb], c0, 0, 0, 0);
                c0 = __builtin_amdgcn_mfma_f32_16x16x32_bf16(w1l[tt][kb], z0h[kb], c0, 0, 0, 0);
                c0 = __builtin_amdgcn_mfma_f32_16x16x32_bf16(w1h[tt][kb], z0l[kb], c0, 0, 0, 0);
                c1 = __builtin_amdgcn_mfma_f32_16x16x32_bf16(w1h[tt][kb], z1h[kb], c1, 0, 0, 0);
                c1 = __builtin_amdgcn_mfma_f32_16x16x32_bf16(w1l[tt][kb], z1h[kb], c1, 0, 0, 0);
                c1 = __builtin_amdgcn_mfma_f32_16x16x32_bf16(w1h[tt][kb], z1l[kb], c1, 0, 0, 0);
            }
            // epilogue: tanh + split, packed b64 writes
            const int jt = 2 * w + tt;
            float tv[4];
            bf16x4 h, l;
            #pragma unroll
            for (int r = 0; r < 4; ++r) tv[r] = tanh_fast(c0[r] + (&b1v[tt].x)[r]);
            split4(tv, &h, &l);
            *(bf16x4*)&sThh[r16][jt * 16 + q * 4] = h;
            *(bf16x4*)&sThl[r16][jt * 16 + q * 4] = l;
            #pragma unroll
            for (int r = 0; r < 4; ++r) tv[r] = tanh_fast(c1[r] + (&b1v[tt].x)[r]);
            split4(tv, &h, &l);
            *(bf16x4*)&sThh[16 + r16][jt * 16 + q * 4] = h;
            *(bf16x4*)&sThl[16 + r16][jt * 16 + q * 4] = l;
        }
        lds_barrier();   // B2: sTh writes -> GEMM2 reads

        // ===== GEMM2 (transposed): D[l][s] = mfma(W2T_frag, th_frag), K=128
        floatx4 d0 = {0.f, 0.f, 0.f, 0.f};
        floatx4 d1 = {0.f, 0.f, 0.f, 0.f};
        #pragma unroll
        for (int kb = 0; kb < 4; ++kb) {
            const bf16x8 t0h = *(const bf16x8*)&sThh[r16][kb * 32 + q * 8];
            const bf16x8 t0l = *(const bf16x8*)&sThl[r16][kb * 32 + q * 8];
            const bf16x8 t1h = *(const bf16x8*)&sThh[16 + r16][kb * 32 + q * 8];
            const bf16x8 t1l = *(const bf16x8*)&sThl[16 + r16][kb * 32 + q * 8];
            d0 = __builtin_amdgcn_mfma_f32_16x16x32_bf16(w2h[kb], t0h, d0, 0, 0, 0);
            d0 = __builtin_amdgcn_mfma_f32_16x16x32_bf16(w2l[kb], t0h, d0, 0, 0, 0);
            d0 = __builtin_amdgcn_mfma_f32_16x16x32_bf16(w2h[kb], t0l, d0, 0, 0, 0);
            d1 = __builtin_amdgcn_mfma_f32_16x16x32_bf16(w2h[kb], t1h, d1, 0, 0, 0);
            d1 = __builtin_amdgcn_mfma_f32_16x16x32_bf16(w2l[kb], t1h, d1, 0, 0, 0);
            d1 = __builtin_amdgcn_mfma_f32_16x16x32_bf16(w2h[kb], t1l, d1, 0, 0, 0);
        }

        // ===== moments: residual from registers, DPP reduce over s (16 lanes)
        float sm[4], sq[4];
        #pragma unroll
        for (int r = 0; r < 4; ++r) {
            const float v0  = d0[r] + (&b2v.x)[r] + zreg0[r];
            const float v1  = d1[r] + (&b2v.x)[r] + zreg1[r];
            const float v1m = m1ok ? v1 : 0.0f;
            sm[r] = reduce16(v0 + v1m);
            sq[r] = reduce16(fmaf(v0, v0, v1m * v1m));
        }

        // ===== Kalman (redundant per lane, registers only)
        float mfv[4], spv[4];
        float4 mf4, mp4, pf4, pp4;
        #pragma unroll
        for (int r = 0; r < 4; ++r) {
            const float mp  = sm[r] * (1.0f / S);
            const float msq = sq[r] * (1.0f / S);
            const float Pp  = qd4[r] + msq - mp * mp;
            const float Jp  = __builtin_amdgcn_rcpf(Pp);
            const float Jf  = Jp + (&Kv.x)[r];
            const float Pf  = __builtin_amdgcn_rcpf(Jf);
            const float mf  = Pf * fmaf(Jp, mp, (&kv.x)[r]);
            mfv[r] = mf;
            spv[r] = __builtin_amdgcn_sqrtf(Pf);
            (&mf4.x)[r] = mf; (&mp4.x)[r] = mp; (&pf4.x)[r] = Pf; (&pp4.x)[r] = Pp;
        }
        if (r16 == 0) {
            *(float4*)pmf             = mf4;
            *(float4*)(pmf + DSEC)    = mp4;
            *(float4*)(pmf + 2*DSEC)  = pf4;
            *(float4*)(pmf + 3*DSEC)  = pp4;
        }
        pmf += L;

        // ===== sample z_t (same thread keeps fp32 z for next step's residual)
        {
            float zv[4];
            #pragma unroll
            for (int r = 0; r < 4; ++r) { zv[r] = fmaf(spv[r], (&nv0.x)[r], mfv[r]); zreg0[r] = zv[r]; }
            bf16x4 h, l; split4(zv, &h, &l);
            *(bf16x4*)&sZh[r16][lc] = h;
            *(bf16x4*)&sZl[r16][lc] = l;
            *(float4*)pz0 = make_float4(zv[0], zv[1], zv[2], zv[3]);
        }
        if (m1ok) {
            float zv[4];
            #pragma unroll
            for (int r = 0; r < 4; ++r) { zv[r] = fmaf(spv[r], (&nv1.x)[r], mfv[r]); zreg1[r] = zv[r]; }
            bf16x4 h, l; split4(zv, &h, &l);
            *(bf16x4*)&sZh[16 + r16][lc] = h;
            *(bf16x4*)&sZl[16 + r16][lc] = l;
            *(float4*)pz1 = make_float4(zv[0], zv[1], zv[2], zv[3]);
        }
        pz0 += L; pz1 += L;
    }
}

extern "C" void kernel_launch(void* const* d_in, const int* in_sizes, int n_in,
                              void* d_out, int out_size, void* d_ws, size_t ws_size,
                              hipStream_t stream) {
    const float* kk      = (const float*)d_in[0];
    const float* KK      = (const float*)d_in[1];
    const float* noise   = (const float*)d_in[2];
    const float* log_Q   = (const float*)d_in[3];
    const float* m_0     = (const float*)d_in[4];
    const float* log_Q_0 = (const float*)d_in[5];
    const float* W1      = (const float*)d_in[6];
    const float* b1      = (const float*)d_in[7];
    const float* W2      = (const float*)d_in[8];
    const float* b2      = (const float*)d_in[9];
    float* outp          = (float*)d_out;

    nlf_kernel<<<dim3(B), dim3(NT), 0, stream>>>(
        kk, KK, noise, log_Q, m_0, log_Q_0, W1, b1, W2, b2, outp);
}